// Round 14
// baseline (1268.910 us; speedup 1.0000x reference)
//
#include <hip/hip_runtime.h>

// Problem constants (shapes fixed by the reference)
#define HP    1017
#define WP    1017
#define NPIX  (HP*WP)          // 1034289
#define N3    (NPIX/3)         // 344763
#define W_IMG 1024
#define EPSV  1e-7f
#define RATE2LN2 0.0013862943611f   // 2*RATE*ln2  (acc computed in log2 domain)
#define LOG2E48  69.2493619627f     // 48*log2(e)
#define LG2EPS  -23.2534966642f     // log2(1e-7)

// temporal blocking geometry (R11-proven)
#define K_ITERS 4
#define RY   16
#define CW   128
#define HALO 8
#define IY   32                // RY + 2*HALO
#define IC   144               // CW + 2*HALO
#define NBX  8
#define NBY  64
#define TBT  512
#define NSLOT 9                // 32*144 = 4608 = 512*9
#define URW  218               // u32 words per staged img row (436 halfs >= 3*IC+4)
#define WMAX ((3*NPIX) >> 1)   // 1551433: last word holding a valid half (3*NPIX-1)

typedef _Float16 half_t;

__device__ __forceinline__ float fast_rcp(float x)  { return __builtin_amdgcn_rcpf(x); }
__device__ __forceinline__ float fast_log2(float x) { return __builtin_amdgcn_logf(x); }
__device__ __forceinline__ float fast_exp2(float x) { return __builtin_amdgcn_exp2f(x); }

// ---------------------------------------------------------------------------
// init: t0 = tlb = max_c(1 - center/A), and pack img_c (fp16) contiguously
// ---------------------------------------------------------------------------
__global__ void init_kernel(const float* __restrict__ img, const float* __restrict__ A,
                            half_t* __restrict__ img_c, float* __restrict__ t0) {
    int b = blockIdx.x * blockDim.x + threadIdx.x;
    int a = blockIdx.y;
    if (b >= WP) return;
    int m = a * WP + b;
    float A0 = A[0], A1 = A[1], A2 = A[2];
    const float* src = img + ((size_t)a * W_IMG + b) * 3;
    img_c[3*m+0] = (half_t)src[0];
    img_c[3*m+1] = (half_t)src[1];
    img_c[3*m+2] = (half_t)src[2];
    const float* cen = img + ((size_t)(a+3) * W_IMG + (b+3)) * 3;
    float t = 1.0f - cen[0] / A0;
    t = fmaxf(t, 1.0f - cen[1] / A1);
    t = fmaxf(t, 1.0f - cen[2] / A2);
    t0[m] = t;
}

// ---------------------------------------------------------------------------
// slot walk: contiguous cells tid + 512*s over the 32x144 tile, division-free.
// ---------------------------------------------------------------------------
template <typename F>
__device__ __forceinline__ void for_slots(int tid, int rbase, int cbase, F f) {
    int i = tid / IC;
    int j = tid - i * IC;
    int arow = rbase + i;
    int col  = cbase + j;
    int m    = arow * WP + col;
    #pragma unroll 1
    for (int s = 0; s < NSLOT; ++s) {
        f(i, j, m, arow, col);
        j += 80; col += 80; m += 3*WP + 80; i += 3; arow += 3;
        if (j >= IC) { j -= IC; col -= IC; m += WP - IC; i += 1; arow += 1; }
    }
}

// ---------------------------------------------------------------------------
// temporal-blocked kernel: 4 GD iterations in LDS.
// lg2 (log2 of guarded t) f32 ping-pong is the primary state; r recovered as
// exp2(-lg2); w0 = exp2(lg2). img staged once per dispatch into uraw (u32-
// aligned per-row windows, parity-corrected). Last dispatch writes dehazed out.
// ---------------------------------------------------------------------------
__global__ __launch_bounds__(TBT, 4) void tb_kernel(
    const float* __restrict__ tin, float* __restrict__ tout,
    const half_t* __restrict__ img_c, const float* __restrict__ A,
    float* __restrict__ out, int last)
{
    __shared__ float    lgl[2][IY][IC];
    __shared__ half_t   sgl[IY][IC];
    __shared__ unsigned uraw[IY][URW];

    // XCD-stripe swizzle: XCD k (= linear%8, HW round-robin) owns by in [8k,8k+8)
    const int l   = blockIdx.x;
    const int xcd = l & 7;
    const int wli = l >> 3;
    const int byy = (xcd << 3) + (wli >> 3);
    const int bxx = wli & 7;
    const int rbase = byy * RY - HALO;
    const int cbase = bxx * CW - HALO;
    const int tid   = threadIdx.x;
    const float A0 = A[0], A1 = A[1], A2 = A[2];

    // ---- stage img tile (coalesced dword loads, clamped) ----
    const int gb00 = 3 * (rbase * WP + cbase);   // half index of cell (0,0) ch0
    const int p00  = gb00 & 1;
    for (int c = tid; c < IY * URW; c += TBT) {
        int i = c / URW, q = c - i * URW;
        int gb = gb00 + i * (3*WP);
        int wq = (gb >> 1) + q;                  // arithmetic shift = floor
        wq = wq < 0 ? 0 : (wq > WMAX ? WMAX : wq);
        uraw[i][q] = ((const unsigned*)img_c)[wq];
    }
    // ---- load t_k -> lg2 ----
    for_slots(tid, rbase, cbase, [&](int i, int j, int m, int arow, int col) {
        float v = 1.0f;
        if ((unsigned)m < (unsigned)NPIX) v = tin[m];
        lgl[0][i][j] = (v <= 0.0f) ? LG2EPS : fast_log2(v);
    });
    __syncthreads();

    #pragma unroll
    for (int lvl = 0; lvl < K_ITERS; ++lvl) {
        float (* __restrict__ lgc)[IC] = lgl[lvl & 1];
        float (* __restrict__ lgn)[IC] = lgl[(lvl & 1) ^ 1];
        const int ms = 2*lvl + 1;
        // --- pass B: sig from r=exp2(-lg2) + staged img ---
        for_slots(tid, rbase, cbase, [&](int i, int j, int m, int arow, int col) {
            float s = 0.0f;
            if (i >= ms && i < IY-ms && j >= ms && j < IC-ms && (unsigned)m < (unsigned)NPIX) {
                float r0 = fast_exp2(-lgc[i][j]);
                float rm = (m > 0)        ? fast_exp2(-lgc[i][j-1]) : r0;
                float rp = (m < NPIX - 1) ? fast_exp2(-lgc[i][j+1]) : r0;
                const half_t* urow = (const half_t*)uraw[i];
                int h = 3*j + ((p00 + i) & 1);
                float fm1 = (float)urow[h-1];
                float f0  = (float)urow[h+0];
                float f1  = (float)urow[h+1];
                float f2  = (float)urow[h+2];
                float f3  = (float)urow[h+3];
                float dm1 = (fm1 - A2) * rm + A2;
                float d0  = (f0  - A0) * r0 + A0;
                float d1  = (f1  - A1) * r0 + A1;
                float d2  = (f2  - A2) * r0 + A2;
                float d3  = (f3  - A0) * rp + A0;
                float y0 = 0.5f * (d1 - dm1);
                float y1 = 0.5f * (d2 - d0);
                float y2 = 0.5f * (d3 - d1);
                if (m == 0      ) y0 = d1 - d0;
                if (m == N3     ) y0 = d1 - d0;
                if (m == 2*N3   ) y0 = d1 - d0;
                if (m == N3 - 1 ) y2 = d2 - d1;
                if (m == 2*N3-1 ) y2 = d2 - d1;
                if (m == NPIX-1 ) y2 = d2 - d1;
                float l2 = sqrtf(y0*y0 + y1*y1 + y2*y2);
                s = fast_rcp(1.0f + fast_exp2(LOG2E48 * (l2 - 0.1f)));
            }
            sgl[i][j] = (half_t)s;
        });
        __syncthreads();
        // --- pass C: t update in log2 domain; lg_new or (last lvl) tout/out ---
        const int mt = 2*lvl + 2;
        for_slots(tid, rbase, cbase, [&](int i, int j, int m, int arow, int col) {
            if (i >= mt && i < IY-mt && j >= mt && j < IC-mt && (unsigned)m < (unsigned)NPIX) {
                int a = arow, b = col;
                if (col < 0)        { a = arow - 1; b = col + WP; }
                else if (col >= WP) { a = arow + 1; b = col - WP; }
                float lgC = lgc[i][j];
                float acc = 0.0f;
                if (b >= 1)
                    acc += (lgC - ((b >= 2)    ? lgc[i][j-2] : 0.0f)) * (float)sgl[i][j-1];
                if (b <= WP-2)
                    acc -= ((((b <= WP-3)) ? lgc[i][j+2] : 0.0f) - lgC) * (float)sgl[i][j+1];
                if (a <= HP-2)
                    acc += (lgC - ((a <= HP-3) ? lgc[i+2][j] : 0.0f)) * (float)sgl[i+1][j];
                if (a >= 1)
                    acc -= (((a >= 2)    ? lgc[i-2][j] : 0.0f) - lgC) * (float)sgl[i-1][j];
                float w0 = fast_exp2(lgC);                // guard(t)
                float rw = fast_exp2(-lgC);               // 1/guard(t)
                float v = w0 - RATE2LN2 * acc * rw;
                if (lvl == K_ITERS - 1) {
                    if (col < WP) {
                        if (last) {                       // fused final dehaze
                            float rr = 1.0f / v;
                            const half_t* urow = (const half_t*)uraw[i];
                            int h = 3*j + ((p00 + i) & 1);
                            int o = 3*m;
                            out[o+0] = ((float)urow[h+0] - A0) * rr + A0;
                            out[o+1] = ((float)urow[h+1] - A1) * rr + A1;
                            out[o+2] = ((float)urow[h+2] - A2) * rr + A2;
                        } else {
                            tout[m] = v;
                        }
                    }
                } else {
                    lgn[i][j] = (v <= 0.0f) ? LG2EPS : fast_log2(v);
                }
            }
        });
        __syncthreads();
    }
}

extern "C" void kernel_launch(void* const* d_in, const int* in_sizes, int n_in,
                              void* d_out, int out_size, void* d_ws, size_t ws_size,
                              hipStream_t stream) {
    const float* img = (const float*)d_in[0];
    const float* A   = (const float*)d_in[1];
    // workspace: t_a[N] f32 | t_b[N] f32 | img_c[3N] f16 (+2 halfs slack in ws)
    float*  ws    = (float*)d_ws;
    float*  t_a   = ws;
    float*  t_b   = t_a + NPIX;
    half_t* img_c = (half_t*)(t_b + NPIX);

    dim3 blk2(256, 1, 1);
    dim3 grd2((WP + 255) / 256, HP, 1);

    hipLaunchKernelGGL(init_kernel, grd2, blk2, 0, stream, img, A, img_c, t_a);

    float* tsrc = t_a;
    float* tdst = t_b;
    for (int d = 0; d < 25; ++d) {               // 25 dispatches x 4 iters = 100
        hipLaunchKernelGGL(tb_kernel, dim3(NBX * NBY), dim3(TBT), 0, stream,
                           tsrc, tdst, img_c, A, (float*)d_out, (d == 24) ? 1 : 0);
        float* tmp = tsrc; tsrc = tdst; tdst = tmp;
    }
}

// Round 15
// 1035.052 us; speedup vs baseline: 1.2259x; 1.2259x over previous
//
#include <hip/hip_runtime.h>

// Problem constants (shapes fixed by the reference)
#define HP    1017
#define WP    1017
#define NPIX  (HP*WP)          // 1034289
#define N3    (NPIX/3)         // 344763
#define W_IMG 1024
#define EPSV  1e-7f

// temporal blocking geometry (occupancy-tuned: 3 blocks/CU)
#define K_ITERS 4
#define RY   16
#define CW   112
#define HALO 8
#define IY   32                // RY + 2*HALO
#define IC   128               // CW + 2*HALO  -> slot stride = exactly 4 rows
#define NBX  10                // 10*112 = 1120 >= 1017
#define NBY  64                // 64*16  = 1024 >= 1017
#define TBT  512
#define NSLOT 8                // 32*128 = 4096 = 512*8

typedef _Float16 half_t;

__device__ __forceinline__ float fast_rcp(float x) { return __builtin_amdgcn_rcpf(x); }

// ---------------------------------------------------------------------------
// init: t0 = tlb = max_c(1 - center/A), and pack img_c (fp16) contiguously
// ---------------------------------------------------------------------------
__global__ void init_kernel(const float* __restrict__ img, const float* __restrict__ A,
                            half_t* __restrict__ img_c, float* __restrict__ t0) {
    int b = blockIdx.x * blockDim.x + threadIdx.x;
    int a = blockIdx.y;
    if (b >= WP) return;
    int m = a * WP + b;
    float A0 = A[0], A1 = A[1], A2 = A[2];
    const float* src = img + ((size_t)a * W_IMG + b) * 3;
    img_c[3*m+0] = (half_t)src[0];
    img_c[3*m+1] = (half_t)src[1];
    img_c[3*m+2] = (half_t)src[2];
    const float* cen = img + ((size_t)(a+3) * W_IMG + (b+3)) * 3;
    float t = 1.0f - cen[0] / A0;
    t = fmaxf(t, 1.0f - cen[1] / A1);
    t = fmaxf(t, 1.0f - cen[2] / A2);
    t0[m] = t;
}

// ---------------------------------------------------------------------------
// temporal-blocked kernel: 4 GD iterations in LDS (R11 math, occupancy-tuned).
// lg f32 ping-pong + sig f16 + r f16. Thread tid owns column j = tid&127 and
// rows i = (tid>>7) + 4s, s<8  => j/col/b and all column-wrap logic hoisted.
// ---------------------------------------------------------------------------
__global__ __launch_bounds__(TBT, 6) void tb_kernel(
    const float* __restrict__ tin, float* __restrict__ tout,
    const half_t* __restrict__ img_c, const float* __restrict__ A)
{
    __shared__ float  lgl[2][IY][IC];   // 32 KiB
    __shared__ half_t sgl[IY][IC];      // 8 KiB
    __shared__ half_t rll[IY][IC];      // 8 KiB   => 48 KiB total, 3 blocks/CU

    const int tid   = threadIdx.x;
    const int i0    = tid >> 7;         // 0..3
    const int j     = tid & 127;        // fixed column
    const int rbase = blockIdx.y * RY - HALO;
    const int cbase = blockIdx.x * CW - HALO;
    const int col   = cbase + j;        // fixed per thread
    const float A0 = A[0], A1 = A[1], A2 = A[2];

    // hoisted column-wrap: cell (i,j) is flat pixel (arow+da, b)
    const int da = (col < 0) ? -1 : ((col >= WP) ? 1 : 0);
    const int b  = col - da * WP;
    const bool bW  = (b >= 1), bW2 = (b >= 2);
    const bool bE  = (b <= WP-2), bE2 = (b <= WP-3);
    const int m00 = (rbase + i0) * WP + col;   // flat m at slot 0

    // ---- load t_k -> lg + r ----
    {
        int m = m00;
        #pragma unroll
        for (int s = 0; s < NSLOT; ++s, m += 4*WP) {
            int i = i0 + 4*s;
            float v = 1.0f;
            if ((unsigned)m < (unsigned)NPIX) v = tin[m];
            rll[i][j]    = (half_t)fast_rcp(v);
            lgl[0][i][j] = __logf(v <= 0.0f ? EPSV : v);
        }
    }
    __syncthreads();

    #pragma unroll
    for (int lvl = 0; lvl < K_ITERS; ++lvl) {
        float (* __restrict__ lgc)[IC] = lgl[lvl & 1];
        float (* __restrict__ lgn)[IC] = lgl[(lvl & 1) ^ 1];
        const int ms = 2*lvl + 1;
        const bool jokB = (j >= ms && j < IC - ms);
        // --- pass B: sig from r (flat +/-1) + img_c (global, L2-served) ---
        {
            int m = m00;
            #pragma unroll 1
            for (int s = 0; s < NSLOT; ++s, m += 4*WP) {
                int i = i0 + 4*s;
                float sv = 0.0f;
                if (jokB && i >= ms && i < IY - ms && (unsigned)m < (unsigned)NPIX) {
                    float r0 = (float)rll[i][j];
                    float rm = (m > 0)        ? (float)rll[i][j-1] : r0;
                    float rp = (m < NPIX - 1) ? (float)rll[i][j+1] : r0;
                    int base = 3 * m;
                    float fm1 = (float)img_c[m > 0        ? base - 1 : 0];
                    float f0  = (float)img_c[base + 0];
                    float f1  = (float)img_c[base + 1];
                    float f2  = (float)img_c[base + 2];
                    float f3  = (float)img_c[m < NPIX - 1 ? base + 3 : base + 2];
                    float dm1 = (fm1 - A2) * rm + A2;
                    float d0  = (f0  - A0) * r0 + A0;
                    float d1  = (f1  - A1) * r0 + A1;
                    float d2  = (f2  - A2) * r0 + A2;
                    float d3  = (f3  - A0) * rp + A0;
                    float y0 = 0.5f * (d1 - dm1);
                    float y1 = 0.5f * (d2 - d0);
                    float y2 = 0.5f * (d3 - d1);
                    if (m == 0      ) y0 = d1 - d0;
                    if (m == N3     ) y0 = d1 - d0;
                    if (m == 2*N3   ) y0 = d1 - d0;
                    if (m == N3 - 1 ) y2 = d2 - d1;
                    if (m == 2*N3-1 ) y2 = d2 - d1;
                    if (m == NPIX-1 ) y2 = d2 - d1;
                    float l2 = sqrtf(y0*y0 + y1*y1 + y2*y2);
                    sv = fast_rcp(1.0f + __expf(48.0f * (l2 - 0.1f)));
                }
                sgl[i][j] = (half_t)sv;
            }
        }
        __syncthreads();
        // --- pass C: t update; w0 = exp(lgC); writes lg_new + r_new (or tout) ---
        const int mt = 2*lvl + 2;
        const bool jokC = (j >= mt && j < IC - mt);
        {
            int m = m00;
            #pragma unroll 1
            for (int s = 0; s < NSLOT; ++s, m += 4*WP) {
                int i = i0 + 4*s;
                if (jokC && i >= mt && i < IY - mt && (unsigned)m < (unsigned)NPIX) {
                    int a = rbase + i + da;
                    float lgC = lgc[i][j];
                    float acc = 0.0f;
                    if (bW)
                        acc += (lgC - (bW2 ? lgc[i][j-2] : 0.0f)) * (float)sgl[i][j-1];
                    if (bE)
                        acc -= ((bE2 ? lgc[i][j+2] : 0.0f) - lgC) * (float)sgl[i][j+1];
                    if (a <= HP-2)
                        acc += (lgC - ((a <= HP-3) ? lgc[i+2][j] : 0.0f)) * (float)sgl[i+1][j];
                    if (a >= 1)
                        acc -= (((a >= 2) ? lgc[i-2][j] : 0.0f) - lgC) * (float)sgl[i-1][j];
                    float w0 = __expf(lgC);                 // exp(log(guard(t))) = guard(t)
                    float rr = (float)rll[i][j];
                    float rw = (rr <= 0.0f) ? 1e7f : rr;    // rcp(guard(t))
                    float v = w0 - 0.001f * 2.0f * acc * rw;
                    if (lvl == K_ITERS - 1) {
                        if (col < WP) tout[m] = v;          // interior => col>=0, m valid
                    } else {
                        lgn[i][j] = __logf(v <= 0.0f ? EPSV : v);
                        rll[i][j] = (half_t)fast_rcp(v);
                    }
                }
            }
        }
        __syncthreads();
    }
}

// ---------------------------------------------------------------------------
// final dehaze from t_100
// ---------------------------------------------------------------------------
__global__ void out_kernel(const float* __restrict__ t, const half_t* __restrict__ img_c,
                           const float* __restrict__ A, float* __restrict__ out) {
    int m = blockIdx.x * blockDim.x + threadIdx.x;
    if (m >= NPIX) return;
    float tv = t[m];
    float A0 = A[0], A1 = A[1], A2 = A[2];
    float r = 1.0f / tv;               // precise div for the final output
    out[3*m+0] = ((float)img_c[3*m+0] - A0) * r + A0;
    out[3*m+1] = ((float)img_c[3*m+1] - A1) * r + A1;
    out[3*m+2] = ((float)img_c[3*m+2] - A2) * r + A2;
}

extern "C" void kernel_launch(void* const* d_in, const int* in_sizes, int n_in,
                              void* d_out, int out_size, void* d_ws, size_t ws_size,
                              hipStream_t stream) {
    const float* img = (const float*)d_in[0];
    const float* A   = (const float*)d_in[1];
    // workspace: t_a[N] f32 | t_b[N] f32 | img_c[3N] f16
    float*  ws    = (float*)d_ws;
    float*  t_a   = ws;
    float*  t_b   = t_a + NPIX;
    half_t* img_c = (half_t*)(t_b + NPIX);

    dim3 blk2(256, 1, 1);
    dim3 grd2((WP + 255) / 256, HP, 1);
    int blk1 = 256;
    int grd1 = (NPIX + blk1 - 1) / blk1;

    hipLaunchKernelGGL(init_kernel, grd2, blk2, 0, stream, img, A, img_c, t_a);

    float* tsrc = t_a;
    float* tdst = t_b;
    for (int d = 0; d < 25; ++d) {               // 25 dispatches x 4 iters = 100
        hipLaunchKernelGGL(tb_kernel, dim3(NBX, NBY), dim3(TBT), 0, stream,
                           tsrc, tdst, img_c, A);
        float* tmp = tsrc; tsrc = tdst; tdst = tmp;
    }
    hipLaunchKernelGGL(out_kernel, dim3(grd1), dim3(blk1), 0, stream,
                       tsrc, img_c, A, (float*)d_out);
}

// Round 16
// 962.626 us; speedup vs baseline: 1.3182x; 1.0752x over previous
//
#include <hip/hip_runtime.h>

// Problem constants (shapes fixed by the reference)
#define HP    1017
#define WP    1017
#define NPIX  (HP*WP)          // 1034289
#define N3    (NPIX/3)         // 344763
#define W_IMG 1024
#define EPSV  1e-7f

// temporal blocking geometry (occupancy-tuned: 3 blocks/CU)
#define K_ITERS 4
#define RY   16
#define CW   112
#define HALO 8
#define IY   32                // RY + 2*HALO
#define IC   128               // CW + 2*HALO  -> slot stride = exactly 4 rows
#define NBX  10                // 10*112 = 1120 >= 1017
#define NBY  64                // 64*16  = 1024 >= 1017
#define TBT  512
#define NSLOT 8                // 32*128 = 4096 = 512*8
#define WQMAX 1551431          // last word wq with wq+2 still a valid/ws-backed word

typedef _Float16 half_t;

__device__ __forceinline__ float fast_rcp(float x) { return __builtin_amdgcn_rcpf(x); }

// ---------------------------------------------------------------------------
// init: t0 = tlb = max_c(1 - center/A), and pack img_c (fp16) contiguously
// ---------------------------------------------------------------------------
__global__ void init_kernel(const float* __restrict__ img, const float* __restrict__ A,
                            half_t* __restrict__ img_c, float* __restrict__ t0) {
    int b = blockIdx.x * blockDim.x + threadIdx.x;
    int a = blockIdx.y;
    if (b >= WP) return;
    int m = a * WP + b;
    float A0 = A[0], A1 = A[1], A2 = A[2];
    const float* src = img + ((size_t)a * W_IMG + b) * 3;
    img_c[3*m+0] = (half_t)src[0];
    img_c[3*m+1] = (half_t)src[1];
    img_c[3*m+2] = (half_t)src[2];
    const float* cen = img + ((size_t)(a+3) * W_IMG + (b+3)) * 3;
    float t = 1.0f - cen[0] / A0;
    t = fmaxf(t, 1.0f - cen[1] / A1);
    t = fmaxf(t, 1.0f - cen[2] / A2);
    t0[m] = t;
}

// ---------------------------------------------------------------------------
// temporal-blocked kernel: 4 GD iterations in LDS (R15 structure).
// NEW: img values hoisted into per-slot registers (pk01=(fm1,f0), pk12=(f1,f2),
// parity-arranged once at stage); only f3 remains a per-level global load.
// ---------------------------------------------------------------------------
__global__ __launch_bounds__(TBT, 6) void tb_kernel(
    const float* __restrict__ tin, float* __restrict__ tout,
    const half_t* __restrict__ img_c, const float* __restrict__ A)
{
    __shared__ float  lgl[2][IY][IC];   // 32 KiB
    __shared__ half_t sgl[IY][IC];      // 8 KiB
    __shared__ half_t rll[IY][IC];      // 8 KiB   => 48 KiB total, 3 blocks/CU

    const int tid   = threadIdx.x;
    const int i0    = tid >> 7;         // 0..3
    const int j     = tid & 127;        // fixed column
    const int rbase = blockIdx.y * RY - HALO;
    const int cbase = blockIdx.x * CW - HALO;
    const int col   = cbase + j;        // fixed per thread
    const float A0 = A[0], A1 = A[1], A2 = A[2];

    // hoisted column-wrap: cell (i,j) is flat pixel (arow+da, b)
    const int da = (col < 0) ? -1 : ((col >= WP) ? 1 : 0);
    const int b  = col - da * WP;
    const bool bW  = (b >= 1), bW2 = (b >= 2);
    const bool bE  = (b <= WP-2), bE2 = (b <= WP-3);
    const int m00 = (rbase + i0) * WP + col;   // flat m at slot 0

    const unsigned* imgw = (const unsigned*)img_c;
    unsigned pk01[NSLOT], pk12[NSLOT];

    // ---- load t_k -> lg + r; stage img window into registers ----
    {
        int m = m00;
        #pragma unroll
        for (int s = 0; s < NSLOT; ++s, m += 4*WP) {
            int i = i0 + 4*s;
            float v = 1.0f;
            if ((unsigned)m < (unsigned)NPIX) v = tin[m];
            rll[i][j]    = (half_t)fast_rcp(v);
            lgl[0][i][j] = __logf(v <= 0.0f ? EPSV : v);
            // img window: halfs 3m-1 .. 3m+2 pre-arranged by parity
            int hb = 3*m - 1;
            int wq, off0;
            if (m <= 0) { wq = 0; off0 = 0; }
            else        { wq = hb >> 1; off0 = 1 + (hb & 1); if (wq > WQMAX) wq = WQMAX; }
            unsigned w0 = imgw[wq], w1 = imgw[wq+1], w2 = imgw[wq+2];
            unsigned pa, pb;
            if (off0 == 0)      { pa = (w0 & 0xffffu) | (w0 << 16); pb = (w0 >> 16) | (w1 << 16); }
            else if (off0 == 1) { pa = w0;                          pb = w1; }
            else                { pa = (w0 >> 16) | (w1 << 16);     pb = (w1 >> 16) | (w2 << 16); }
            pk01[s] = pa; pk12[s] = pb;
        }
    }
    __syncthreads();

    #pragma unroll
    for (int lvl = 0; lvl < K_ITERS; ++lvl) {
        float (* __restrict__ lgc)[IC] = lgl[lvl & 1];
        float (* __restrict__ lgn)[IC] = lgl[(lvl & 1) ^ 1];
        const int ms = 2*lvl + 1;
        const bool jokB = (j >= ms && j < IC - ms);
        // --- pass B: sig from r (flat +/-1) + register-staged img ---
        {
            int m = m00;
            #pragma unroll
            for (int s = 0; s < NSLOT; ++s, m += 4*WP) {
                int i = i0 + 4*s;
                float sv = 0.0f;
                if (jokB && i >= ms && i < IY - ms && (unsigned)m < (unsigned)NPIX) {
                    float r0 = (float)rll[i][j];
                    float rm = (m > 0)        ? (float)rll[i][j-1] : r0;
                    float rp = (m < NPIX - 1) ? (float)rll[i][j+1] : r0;
                    union { unsigned u; half_t h[2]; } ua, ub;
                    ua.u = pk01[s]; ub.u = pk12[s];
                    float fm1 = (float)ua.h[0];
                    float f0  = (float)ua.h[1];
                    float f1  = (float)ub.h[0];
                    float f2  = (float)ub.h[1];
                    float f3  = (float)img_c[m < NPIX - 1 ? 3*m + 3 : 3*m + 2];
                    float dm1 = (fm1 - A2) * rm + A2;
                    float d0  = (f0  - A0) * r0 + A0;
                    float d1  = (f1  - A1) * r0 + A1;
                    float d2  = (f2  - A2) * r0 + A2;
                    float d3  = (f3  - A0) * rp + A0;
                    float y0 = 0.5f * (d1 - dm1);
                    float y1 = 0.5f * (d2 - d0);
                    float y2 = 0.5f * (d3 - d1);
                    if (m == 0      ) y0 = d1 - d0;
                    if (m == N3     ) y0 = d1 - d0;
                    if (m == 2*N3   ) y0 = d1 - d0;
                    if (m == N3 - 1 ) y2 = d2 - d1;
                    if (m == 2*N3-1 ) y2 = d2 - d1;
                    if (m == NPIX-1 ) y2 = d2 - d1;
                    float l2 = sqrtf(y0*y0 + y1*y1 + y2*y2);
                    sv = fast_rcp(1.0f + __expf(48.0f * (l2 - 0.1f)));
                }
                sgl[i][j] = (half_t)sv;
            }
        }
        __syncthreads();
        // --- pass C: t update; w0 = exp(lgC); writes lg_new + r_new (or tout) ---
        const int mt = 2*lvl + 2;
        const bool jokC = (j >= mt && j < IC - mt);
        {
            int m = m00;
            #pragma unroll 1
            for (int s = 0; s < NSLOT; ++s, m += 4*WP) {
                int i = i0 + 4*s;
                if (jokC && i >= mt && i < IY - mt && (unsigned)m < (unsigned)NPIX) {
                    int a = rbase + i + da;
                    float lgC = lgc[i][j];
                    float acc = 0.0f;
                    if (bW)
                        acc += (lgC - (bW2 ? lgc[i][j-2] : 0.0f)) * (float)sgl[i][j-1];
                    if (bE)
                        acc -= ((bE2 ? lgc[i][j+2] : 0.0f) - lgC) * (float)sgl[i][j+1];
                    if (a <= HP-2)
                        acc += (lgC - ((a <= HP-3) ? lgc[i+2][j] : 0.0f)) * (float)sgl[i+1][j];
                    if (a >= 1)
                        acc -= (((a >= 2) ? lgc[i-2][j] : 0.0f) - lgC) * (float)sgl[i-1][j];
                    float w0 = __expf(lgC);                 // exp(log(guard(t))) = guard(t)
                    float rr = (float)rll[i][j];
                    float rw = (rr <= 0.0f) ? 1e7f : rr;    // rcp(guard(t))
                    float v = w0 - 0.001f * 2.0f * acc * rw;
                    if (lvl == K_ITERS - 1) {
                        if (col < WP) tout[m] = v;          // interior => col>=0, m valid
                    } else {
                        lgn[i][j] = __logf(v <= 0.0f ? EPSV : v);
                        rll[i][j] = (half_t)fast_rcp(v);
                    }
                }
            }
        }
        __syncthreads();
    }
}

// ---------------------------------------------------------------------------
// final dehaze from t_100
// ---------------------------------------------------------------------------
__global__ void out_kernel(const float* __restrict__ t, const half_t* __restrict__ img_c,
                           const float* __restrict__ A, float* __restrict__ out) {
    int m = blockIdx.x * blockDim.x + threadIdx.x;
    if (m >= NPIX) return;
    float tv = t[m];
    float A0 = A[0], A1 = A[1], A2 = A[2];
    float r = 1.0f / tv;               // precise div for the final output
    out[3*m+0] = ((float)img_c[3*m+0] - A0) * r + A0;
    out[3*m+1] = ((float)img_c[3*m+1] - A1) * r + A1;
    out[3*m+2] = ((float)img_c[3*m+2] - A2) * r + A2;
}

extern "C" void kernel_launch(void* const* d_in, const int* in_sizes, int n_in,
                              void* d_out, int out_size, void* d_ws, size_t ws_size,
                              hipStream_t stream) {
    const float* img = (const float*)d_in[0];
    const float* A   = (const float*)d_in[1];
    // workspace: t_a[N] f32 | t_b[N] f32 | img_c[3N] f16 (+slack)
    float*  ws    = (float*)d_ws;
    float*  t_a   = ws;
    float*  t_b   = t_a + NPIX;
    half_t* img_c = (half_t*)(t_b + NPIX);

    dim3 blk2(256, 1, 1);
    dim3 grd2((WP + 255) / 256, HP, 1);
    int blk1 = 256;
    int grd1 = (NPIX + blk1 - 1) / blk1;

    hipLaunchKernelGGL(init_kernel, grd2, blk2, 0, stream, img, A, img_c, t_a);

    float* tsrc = t_a;
    float* tdst = t_b;
    for (int d = 0; d < 25; ++d) {               // 25 dispatches x 4 iters = 100
        hipLaunchKernelGGL(tb_kernel, dim3(NBX, NBY), dim3(TBT), 0, stream,
                           tsrc, tdst, img_c, A);
        float* tmp = tsrc; tsrc = tdst; tdst = tmp;
    }
    hipLaunchKernelGGL(out_kernel, dim3(grd1), dim3(blk1), 0, stream,
                       tsrc, img_c, A, (float*)d_out);
}